// Round 2
// baseline (2029.952 us; speedup 1.0000x reference)
//
#include <hip/hip_runtime.h>
#include <math.h>

#define NN 50000
#define EE 800000
#define HIDDEN 128
#define NGRAPH 50

// ---------------- CSR build ----------------
__global__ void k_deg(const int* __restrict__ eidx, int* __restrict__ cnt) {
    int e = blockIdx.x * blockDim.x + threadIdx.x;
    if (e < EE) atomicAdd(&cnt[eidx[EE + e]], 1);
}

__global__ void k_scan(const int* __restrict__ deg, int* __restrict__ row_ptr) {
    __shared__ int buf[1024];
    __shared__ int carry_s;
    int t = threadIdx.x;
    if (t == 0) carry_s = 0;
    __syncthreads();
    for (int base = 0; base < NN; base += 1024) {
        int i = base + t;
        int v = (i < NN) ? deg[i] : 0;
        buf[t] = v;
        __syncthreads();
        int incl = v;
        for (int o = 1; o < 1024; o <<= 1) {
            int add = (t >= o) ? buf[t - o] : 0;
            __syncthreads();
            incl += add;
            buf[t] = incl;
            __syncthreads();
        }
        int carry = carry_s;
        if (i < NN) row_ptr[i] = carry + incl - v;
        int total = buf[1023];
        __syncthreads();
        if (t == 0) carry_s = carry + total;
        __syncthreads();
    }
    if (t == 0) row_ptr[NN] = carry_s;
}

__global__ void k_scatter(const int* __restrict__ eidx, const int* __restrict__ row_ptr,
                          int* __restrict__ cur, int* __restrict__ elist) {
    int e = blockIdx.x * blockDim.x + threadIdx.x;
    if (e < EE) {
        int d = eidx[EE + e];
        int p = atomicAdd(&cur[d], 1);
        elist[row_ptr[d] + p] = e;
    }
}

// ---------------- fused 4-way GEMM: q,k,v,xr = X @ {Wq,Wk,Wv,Wskip} + b ----------------
__global__ __launch_bounds__(256) void k_gemm4(
    const float* __restrict__ X,
    const float* __restrict__ Wq, const float* __restrict__ bq,
    const float* __restrict__ Wk, const float* __restrict__ bk,
    const float* __restrict__ Wv, const float* __restrict__ bv,
    const float* __restrict__ Ws, const float* __restrict__ bs,
    float* __restrict__ qo, float* __restrict__ ko,
    float* __restrict__ vo, float* __restrict__ xro)
{
    __shared__ float xs[64][132];
    int t = threadIdx.x;
    int m0 = blockIdx.x * 64;
#pragma unroll
    for (int i = 0; i < 8; ++i) {
        int f = t + 256 * i;          // float4 index within 64x32
        int r = f >> 5, c4 = (f & 31) << 2;
        float4 val = make_float4(0.f, 0.f, 0.f, 0.f);
        if (m0 + r < NN) val = *(const float4*)&X[(size_t)(m0 + r) * 128 + c4];
        *(float4*)&xs[r][c4] = val;
    }
    __syncthreads();
    int cg = t & 15, ng = t >> 4;
    int c0 = cg * 8;
    int mb = ng * 4;
    const float* Wm[4] = {Wq, Wk, Wv, Ws};
    const float* bm[4] = {bq, bk, bv, bs};
    float* om[4] = {qo, ko, vo, xro};
#pragma unroll
    for (int w = 0; w < 4; ++w) {
        const float* __restrict__ W = Wm[w];
        float acc[4][8];
#pragma unroll
        for (int i = 0; i < 4; i++)
#pragma unroll
            for (int j = 0; j < 8; j++) acc[i][j] = 0.f;
        for (int k = 0; k < 128; k += 4) {
            float4 xa[4];
#pragma unroll
            for (int i = 0; i < 4; i++) xa[i] = *(const float4*)&xs[mb + i][k];
            float4 wr[4][2];
#pragma unroll
            for (int kk = 0; kk < 4; kk++) {
                wr[kk][0] = *(const float4*)&W[(k + kk) * 128 + c0];
                wr[kk][1] = *(const float4*)&W[(k + kk) * 128 + c0 + 4];
            }
#pragma unroll
            for (int kk = 0; kk < 4; kk++) {
                float wv[8] = {wr[kk][0].x, wr[kk][0].y, wr[kk][0].z, wr[kk][0].w,
                               wr[kk][1].x, wr[kk][1].y, wr[kk][1].z, wr[kk][1].w};
#pragma unroll
                for (int i = 0; i < 4; i++) {
                    float xv = ((const float*)&xa[i])[kk];
#pragma unroll
                    for (int j = 0; j < 8; j++) acc[i][j] = fmaf(xv, wv[j], acc[i][j]);
                }
            }
        }
        float4 b0 = *(const float4*)&bm[w][c0];
        float4 b1 = *(const float4*)&bm[w][c0 + 4];
#pragma unroll
        for (int i = 0; i < 4; i++) {
            int node = m0 + mb + i;
            if (node < NN) {
                float4 o0 = make_float4(acc[i][0] + b0.x, acc[i][1] + b0.y,
                                        acc[i][2] + b0.z, acc[i][3] + b0.w);
                float4 o1 = make_float4(acc[i][4] + b1.x, acc[i][5] + b1.y,
                                        acc[i][6] + b1.z, acc[i][7] + b1.w);
                *(float4*)&om[w][(size_t)node * 128 + c0] = o0;
                *(float4*)&om[w][(size_t)node * 128 + c0 + 4] = o1;
            }
        }
    }
}

// ---------------- attention + gate + BN-stats (one wave per dst node) ----------------
__global__ __launch_bounds__(256) void k_attn(
    const float* __restrict__ q, const float* __restrict__ k,
    const float* __restrict__ v, const float* __restrict__ xr,
    const int* __restrict__ eidx, const float* __restrict__ eattr,
    const int* __restrict__ row_ptr, const int* __restrict__ elist,
    const float* __restrict__ We, const float* __restrict__ be,
    const float* __restrict__ Wb,
    float* __restrict__ out2, float* __restrict__ bn_accum)
{
    int t = threadIdx.x;
    int lane = t & 63;
    int wid = t >> 6;
    int gwave = blockIdx.x * 4 + wid;
    int nwaves = gridDim.x * 4;
    int ch = lane * 2;
    float2 we0 = *(const float2*)&We[ch];
    float2 we1 = *(const float2*)&We[128 + ch];
    float2 beL = *(const float2*)&be[ch];
    float2 wb_o = *(const float2*)&Wb[ch];
    float2 wb_r = *(const float2*)&Wb[128 + ch];
    float2 wb_d = *(const float2*)&Wb[256 + ch];
    const float scale = 0.17677669529663687f;   // 1/sqrt(32)
    float bnsx = 0.f, bnsy = 0.f, bnqx = 0.f, bnqy = 0.f;

    for (int n = gwave; n < NN; n += nwaves) {
        int rs = row_ptr[n], re = row_ptr[n + 1];
        float2 qv = *(const float2*)&q[(size_t)n * 128 + ch];
        float den = 0.f;
        float ax = 0.f, ay = 0.f;
        for (int idx = rs; idx < re; ++idx) {
            int e = elist[idx];
            int s = eidx[e];
            float2 ea = *(const float2*)&eattr[2 * (size_t)e];
            float ex_ = ea.x * we0.x + ea.y * we1.x + beL.x;
            float ey_ = ea.x * we0.y + ea.y * we1.y + beL.y;
            float2 kv = *(const float2*)&k[(size_t)s * 128 + ch];
            float2 vv = *(const float2*)&v[(size_t)s * 128 + ch];
            float p = qv.x * (kv.x + ex_) + qv.y * (kv.y + ey_);
            p += __shfl_xor(p, 1);
            p += __shfl_xor(p, 2);
            p += __shfl_xor(p, 4);
            p += __shfl_xor(p, 8);
            float exv = __expf(p * scale);
            den += exv;
            ax = fmaf(exv, vv.x + ex_, ax);
            ay = fmaf(exv, vv.y + ey_, ay);
        }
        float rden = 1.f / (den + 1e-16f);
        ax *= rden; ay *= rden;
        // beta gate
        float2 xv = *(const float2*)&xr[(size_t)n * 128 + ch];
        float gp = ax * wb_o.x + ay * wb_o.y + xv.x * wb_r.x + xv.y * wb_r.y
                 + (ax - xv.x) * wb_d.x + (ay - xv.y) * wb_d.y;
        gp += __shfl_xor(gp, 1);
        gp += __shfl_xor(gp, 2);
        gp += __shfl_xor(gp, 4);
        gp += __shfl_xor(gp, 8);
        gp += __shfl_xor(gp, 16);
        gp += __shfl_xor(gp, 32);
        float gate = 1.f / (1.f + __expf(-gp));
        float ox = gate * xv.x + (1.f - gate) * ax;
        float oy = gate * xv.y + (1.f - gate) * ay;
        float2 o2 = make_float2(ox, oy);
        *(float2*)&out2[(size_t)n * 128 + ch] = o2;
        bnsx += ox; bnsy += oy;
        bnqx = fmaf(ox, ox, bnqx); bnqy = fmaf(oy, oy, bnqy);
    }
    // block-level BN partial reduce
    __shared__ float s_sum[2][256], s_sq[2][256];
    s_sum[0][t] = bnsx; s_sum[1][t] = bnsy;
    s_sq[0][t] = bnqx;  s_sq[1][t] = bnqy;
    __syncthreads();
    if (t < 64) {
        float sx = s_sum[0][t] + s_sum[0][64 + t] + s_sum[0][128 + t] + s_sum[0][192 + t];
        float sy = s_sum[1][t] + s_sum[1][64 + t] + s_sum[1][128 + t] + s_sum[1][192 + t];
        float qx = s_sq[0][t] + s_sq[0][64 + t] + s_sq[0][128 + t] + s_sq[0][192 + t];
        float qy = s_sq[1][t] + s_sq[1][64 + t] + s_sq[1][128 + t] + s_sq[1][192 + t];
        int c = 2 * t;
        atomicAdd(&bn_accum[c], sx);
        atomicAdd(&bn_accum[c + 1], sy);
        atomicAdd(&bn_accum[128 + c], qx);
        atomicAdd(&bn_accum[128 + c + 1], qy);
    }
}

// ---------------- BN finalize: fold into affine a,b ----------------
__global__ void k_bnfin(const float* __restrict__ bn_accum, const float* __restrict__ gamma,
                        const float* __restrict__ beta, float* __restrict__ ab) {
    int c = threadIdx.x;
    if (c < 128) {
        float mu = bn_accum[c] * (1.f / NN);
        float var = bn_accum[128 + c] * (1.f / NN) - mu * mu;
        float inv = rsqrtf(var + 1e-5f);
        float a = inv * gamma[c];
        ab[c] = a;
        ab[128 + c] = beta[c] - mu * a;
    }
}

// ---------------- affine + ELU (in place) ----------------
__global__ __launch_bounds__(256) void k_elu(const float* __restrict__ ab, float* __restrict__ x) {
    int i = blockIdx.x * blockDim.x + threadIdx.x;   // float4 index
    if (i < NN * 128 / 4) {
        int c0 = (i * 4) & 127;
        float4 vv = *(float4*)&x[(size_t)i * 4];
        float4 a = *(const float4*)&ab[c0];
        float4 b = *(const float4*)&ab[128 + c0];
        float z;
        z = fmaf(vv.x, a.x, b.x); vv.x = z > 0.f ? z : expm1f(z);
        z = fmaf(vv.y, a.y, b.y); vv.y = z > 0.f ? z : expm1f(z);
        z = fmaf(vv.z, a.z, b.z); vv.z = z > 0.f ? z : expm1f(z);
        z = fmaf(vv.w, a.w, b.w); vv.w = z > 0.f ? z : expm1f(z);
        *(float4*)&x[(size_t)i * 4] = vv;
    }
}

// ---------------- readout: per-node dot with Wout, per-graph mean ----------------
__global__ __launch_bounds__(256) void k_pool(const float* __restrict__ x, const float* __restrict__ Wout,
                                              const int* __restrict__ batch,
                                              float* __restrict__ gsum, int* __restrict__ gcnt) {
    int t = threadIdx.x;
    int lane = t & 63;
    int wid = t >> 6;
    int gwave = blockIdx.x * 4 + wid;
    int nwaves = gridDim.x * 4;
    int ch = lane * 2;
    float2 wo = *(const float2*)&Wout[ch];
    for (int n = gwave; n < NN; n += nwaves) {
        float2 xv = *(const float2*)&x[(size_t)n * 128 + ch];
        float p = xv.x * wo.x + xv.y * wo.y;
        p += __shfl_xor(p, 1);
        p += __shfl_xor(p, 2);
        p += __shfl_xor(p, 4);
        p += __shfl_xor(p, 8);
        p += __shfl_xor(p, 16);
        p += __shfl_xor(p, 32);
        if (lane == 0) {
            int g = batch[n];
            atomicAdd(&gsum[g], p);
            atomicAdd(&gcnt[g], 1);
        }
    }
}

__global__ void k_final(const float* __restrict__ gsum, const int* __restrict__ gcnt,
                        const float* __restrict__ bout, const float* __restrict__ obias,
                        float* __restrict__ out) {
    int g = threadIdx.x;
    if (g < NGRAPH) out[g] = gsum[g] / fmaxf((float)gcnt[g], 1.f) + bout[0] + obias[0];
}

extern "C" void kernel_launch(void* const* d_in, const int* in_sizes, int n_in,
                              void* d_out, int out_size, void* d_ws, size_t ws_size,
                              hipStream_t stream) {
    const float* x_in       = (const float*)d_in[0];
    const int* eidx         = (const int*)d_in[1];
    const float* eattr      = (const float*)d_in[2];
    const int* batch        = (const int*)d_in[3];
    const float* Wq         = (const float*)d_in[4];
    const float* bq         = (const float*)d_in[5];
    const float* Wk         = (const float*)d_in[6];
    const float* bk         = (const float*)d_in[7];
    const float* Wv         = (const float*)d_in[8];
    const float* bv         = (const float*)d_in[9];
    const float* We         = (const float*)d_in[10];
    const float* be         = (const float*)d_in[11];
    const float* Wskip      = (const float*)d_in[12];
    const float* bskip      = (const float*)d_in[13];
    const float* Wbeta      = (const float*)d_in[14];
    const float* bn_gamma   = (const float*)d_in[15];
    const float* bn_beta    = (const float*)d_in[16];
    const float* Wout       = (const float*)d_in[17];
    const float* bout       = (const float*)d_in[18];
    const float* obias      = (const float*)d_in[19];
    float* out = (float*)d_out;

    char* ws = (char*)d_ws;
    size_t off = 0;
    auto alloc = [&](size_t bytes) -> void* {
        off = (off + 255) & ~(size_t)255;
        void* p = ws + off;
        off += bytes;
        return p;
    };
    const size_t NF = (size_t)NN * 128 * sizeof(float);
    float* xbuf   = (float*)alloc(NF);
    float* qb     = (float*)alloc(NF);
    float* kb     = (float*)alloc(NF);
    float* vb     = (float*)alloc(NF);
    float* xrb    = (float*)alloc(NF);
    int* row_ptr  = (int*)alloc((NN + 1) * sizeof(int));
    int* cnt      = (int*)alloc(NN * sizeof(int));
    int* elist    = (int*)alloc(EE * sizeof(int));
    float* bn_acc = (float*)alloc(256 * sizeof(float));
    float* bn_ab  = (float*)alloc(256 * sizeof(float));
    float* gsum   = (float*)alloc(64 * sizeof(float));
    int* gcnt     = (int*)alloc(64 * sizeof(int));
    (void)ws_size; (void)n_in; (void)in_sizes; (void)out_size;

    // ---- CSR build (dst -> edge ids) ----
    hipMemsetAsync(cnt, 0, NN * sizeof(int), stream);
    k_deg<<<(EE + 255) / 256, 256, 0, stream>>>(eidx, cnt);
    k_scan<<<1, 1024, 0, stream>>>(cnt, row_ptr);
    hipMemsetAsync(cnt, 0, NN * sizeof(int), stream);
    k_scatter<<<(EE + 255) / 256, 256, 0, stream>>>(eidx, row_ptr, cnt, elist);

    // ---- layers ----
    for (int l = 0; l < 3; ++l) {
        const float* Xl = (l == 0) ? x_in : xbuf;
        hipMemsetAsync(bn_acc, 0, 256 * sizeof(float), stream);
        k_gemm4<<<(NN + 63) / 64, 256, 0, stream>>>(
            Xl,
            Wq + (size_t)l * 16384, bq + l * 128,
            Wk + (size_t)l * 16384, bk + l * 128,
            Wv + (size_t)l * 16384, bv + l * 128,
            Wskip + (size_t)l * 16384, bskip + l * 128,
            qb, kb, vb, xrb);
        k_attn<<<3125, 256, 0, stream>>>(
            qb, kb, vb, xrb, eidx, eattr, row_ptr, elist,
            We + (size_t)l * 256, be + l * 128, Wbeta + (size_t)l * 384,
            xbuf, bn_acc);
        k_bnfin<<<1, 128, 0, stream>>>(bn_acc, bn_gamma + l * 128, bn_beta + l * 128, bn_ab);
        k_elu<<<(NN * 128 / 4 + 255) / 256, 256, 0, stream>>>(bn_ab, xbuf);
    }

    // ---- readout ----
    hipMemsetAsync(gsum, 0, 64 * sizeof(float), stream);
    hipMemsetAsync(gcnt, 0, 64 * sizeof(int), stream);
    k_pool<<<782, 256, 0, stream>>>(xbuf, Wout, batch, gsum, gcnt);
    k_final<<<1, 64, 0, stream>>>(gsum, gcnt, bout, obias, out);
}

// Round 3
// 1427.356 us; speedup vs baseline: 1.4222x; 1.4222x over previous
//
#include <hip/hip_runtime.h>
#include <hip/hip_fp16.h>
#include <math.h>

#define NN 50000
#define EE 800000
#define HIDDEN 128
#define NGRAPH 50

struct __align__(8) kv8 { __half2 k2, v2; };

// ---------------- CSR build ----------------
__global__ void k_deg(const int* __restrict__ eidx, int* __restrict__ cnt) {
    int e = blockIdx.x * blockDim.x + threadIdx.x;
    if (e < EE) atomicAdd(&cnt[eidx[EE + e]], 1);
}

__global__ void k_scan(const int* __restrict__ deg, int* __restrict__ row_ptr) {
    __shared__ int wsum[16];
    __shared__ int carry_s;
    int t = threadIdx.x;
    int lane = t & 63, w = t >> 6;
    if (t == 0) carry_s = 0;
    __syncthreads();
    for (int base = 0; base < NN; base += 1024) {
        int i = base + t;
        int v = (i < NN) ? deg[i] : 0;
        int s = v;
#pragma unroll
        for (int o = 1; o < 64; o <<= 1) {
            int u = __shfl_up(s, o);
            if (lane >= o) s += u;
        }
        if (lane == 63) wsum[w] = s;
        __syncthreads();
        if (w == 0) {
            int ws = (lane < 16) ? wsum[lane] : 0;
#pragma unroll
            for (int o = 1; o < 16; o <<= 1) {
                int u = __shfl_up(ws, o);
                if (lane >= o) ws += u;
            }
            if (lane < 16) wsum[lane] = ws;
        }
        __syncthreads();
        int wpre = (w == 0) ? 0 : wsum[w - 1];
        int carry = carry_s;
        if (i < NN) row_ptr[i] = carry + wpre + s - v;   // exclusive scan
        __syncthreads();
        if (t == 1023) carry_s = carry + wpre + s;
        __syncthreads();
    }
    if (t == 0) row_ptr[NN] = carry_s;
}

__global__ void k_scatter(const int* __restrict__ eidx, const int* __restrict__ row_ptr,
                          int* __restrict__ cur, int* __restrict__ elist) {
    int e = blockIdx.x * blockDim.x + threadIdx.x;
    if (e < EE) {
        int d = eidx[EE + e];
        int p = atomicAdd(&cur[d], 1);
        elist[row_ptr[d] + p] = e;
    }
}

// ---- fused 4-way GEMM: q,xr fp32; k,v packed fp16 interleaved. Optional BN-affine+ELU on input. ----
__global__ __launch_bounds__(256) void k_gemm4(
    const float* __restrict__ X,
    const float* __restrict__ Wq, const float* __restrict__ bq,
    const float* __restrict__ Wk, const float* __restrict__ bk,
    const float* __restrict__ Wv, const float* __restrict__ bv,
    const float* __restrict__ Ws, const float* __restrict__ bs,
    const float* __restrict__ ab, int use_ab,
    float* __restrict__ qo, __half* __restrict__ kvh, float* __restrict__ xro)
{
    __shared__ float xs[64][132];
    int t = threadIdx.x;
    int m0 = blockIdx.x * 64;
#pragma unroll
    for (int i = 0; i < 8; ++i) {
        int f = t + 256 * i;          // float4 index within 64x32
        int r = f >> 5, c4 = (f & 31) << 2;
        float4 val = make_float4(0.f, 0.f, 0.f, 0.f);
        if (m0 + r < NN) val = *(const float4*)&X[(size_t)(m0 + r) * 128 + c4];
        if (use_ab) {
            float4 a = *(const float4*)&ab[c4];
            float4 bb = *(const float4*)&ab[128 + c4];
            float z;
            z = fmaf(val.x, a.x, bb.x); val.x = z > 0.f ? z : expm1f(z);
            z = fmaf(val.y, a.y, bb.y); val.y = z > 0.f ? z : expm1f(z);
            z = fmaf(val.z, a.z, bb.z); val.z = z > 0.f ? z : expm1f(z);
            z = fmaf(val.w, a.w, bb.w); val.w = z > 0.f ? z : expm1f(z);
        }
        *(float4*)&xs[r][c4] = val;
    }
    __syncthreads();
    int cg = t & 15, ng = t >> 4;
    int c0 = cg * 8;
    int mb = ng * 4;
    const float* Wm[4] = {Wq, Wk, Wv, Ws};
    const float* bm[4] = {bq, bk, bv, bs};
    __half2 khold[4][4];
#pragma unroll
    for (int w = 0; w < 4; ++w) {
        const float* __restrict__ W = Wm[w];
        float acc[4][8];
#pragma unroll
        for (int i = 0; i < 4; i++)
#pragma unroll
            for (int j = 0; j < 8; j++) acc[i][j] = 0.f;
        for (int k = 0; k < 128; k += 4) {
            float4 xa[4];
#pragma unroll
            for (int i = 0; i < 4; i++) xa[i] = *(const float4*)&xs[mb + i][k];
            float4 wr[4][2];
#pragma unroll
            for (int kk = 0; kk < 4; kk++) {
                wr[kk][0] = *(const float4*)&W[(k + kk) * 128 + c0];
                wr[kk][1] = *(const float4*)&W[(k + kk) * 128 + c0 + 4];
            }
#pragma unroll
            for (int kk = 0; kk < 4; kk++) {
                float wv[8] = {wr[kk][0].x, wr[kk][0].y, wr[kk][0].z, wr[kk][0].w,
                               wr[kk][1].x, wr[kk][1].y, wr[kk][1].z, wr[kk][1].w};
#pragma unroll
                for (int i = 0; i < 4; i++) {
                    float xv = ((const float*)&xa[i])[kk];
#pragma unroll
                    for (int j = 0; j < 8; j++) acc[i][j] = fmaf(xv, wv[j], acc[i][j]);
                }
            }
        }
        float bb[8];
        *(float4*)&bb[0] = *(const float4*)&bm[w][c0];
        *(float4*)&bb[4] = *(const float4*)&bm[w][c0 + 4];
        if (w == 0 || w == 3) {
            float* om = (w == 0) ? qo : xro;
#pragma unroll
            for (int i = 0; i < 4; i++) {
                int node = m0 + mb + i;
                if (node < NN) {
                    float4 o0 = make_float4(acc[i][0] + bb[0], acc[i][1] + bb[1],
                                            acc[i][2] + bb[2], acc[i][3] + bb[3]);
                    float4 o1 = make_float4(acc[i][4] + bb[4], acc[i][5] + bb[5],
                                            acc[i][6] + bb[6], acc[i][7] + bb[7]);
                    *(float4*)&om[(size_t)node * 128 + c0] = o0;
                    *(float4*)&om[(size_t)node * 128 + c0 + 4] = o1;
                }
            }
        } else if (w == 1) {
#pragma unroll
            for (int i = 0; i < 4; i++)
#pragma unroll
                for (int j = 0; j < 4; j++)
                    khold[i][j] = __float22half2_rn(
                        make_float2(acc[i][2 * j] + bb[2 * j], acc[i][2 * j + 1] + bb[2 * j + 1]));
        } else {  // w == 2: interleaved {k0,k1,v0,v1} per channel pair
#pragma unroll
            for (int i = 0; i < 4; i++) {
                int node = m0 + mb + i;
                if (node < NN) {
#pragma unroll
                    for (int j = 0; j < 4; j++) {
                        kv8 p;
                        p.k2 = khold[i][j];
                        p.v2 = __float22half2_rn(
                            make_float2(acc[i][2 * j] + bb[2 * j], acc[i][2 * j + 1] + bb[2 * j + 1]));
                        *(kv8*)&kvh[(size_t)node * 256 + 2 * c0 + 4 * j] = p;
                    }
                }
            }
        }
    }
}

// ---------------- attention + gate + BN-stats (one wave per dst node) ----------------
__global__ __launch_bounds__(256) void k_attn(
    const float* __restrict__ q, const __half* __restrict__ kvh,
    const float* __restrict__ xr,
    const int* __restrict__ eidx, const float* __restrict__ eattr,
    const int* __restrict__ row_ptr, const int* __restrict__ elist,
    const float* __restrict__ We, const float* __restrict__ be,
    const float* __restrict__ Wb,
    float* __restrict__ out2, float* __restrict__ bn_accum)
{
    int t = threadIdx.x;
    int lane = t & 63;
    int wid = t >> 6;
    int gwave = blockIdx.x * 4 + wid;
    int nwaves = gridDim.x * 4;
    int ch = lane * 2;
    float2 we0 = *(const float2*)&We[ch];
    float2 we1 = *(const float2*)&We[128 + ch];
    float2 beL = *(const float2*)&be[ch];
    float2 wb_o = *(const float2*)&Wb[ch];
    float2 wb_r = *(const float2*)&Wb[128 + ch];
    float2 wb_d = *(const float2*)&Wb[256 + ch];
    const float scale = 0.17677669529663687f;   // 1/sqrt(32)
    float bnsx = 0.f, bnsy = 0.f, bnqx = 0.f, bnqy = 0.f;

    for (int n = gwave; n < NN; n += nwaves) {
        int rs = row_ptr[n], re = row_ptr[n + 1];
        float2 qv = *(const float2*)&q[(size_t)n * 128 + ch];
        float den = 0.f;
        float ax = 0.f, ay = 0.f;
        int s_n = 0;
        float2 ea_n = make_float2(0.f, 0.f);
        if (rs < re) {
            int e0 = elist[rs];
            s_n = eidx[e0];
            ea_n = *(const float2*)&eattr[2 * (size_t)e0];
        }
        for (int idx = rs; idx < re; ++idx) {
            int s = s_n;
            float2 ea = ea_n;
            kv8 kk = *(const kv8*)&kvh[(size_t)s * 256 + 4 * lane];   // issue gather early
            if (idx + 1 < re) {                                       // prefetch next indices
                int e1 = elist[idx + 1];
                s_n = eidx[e1];
                ea_n = *(const float2*)&eattr[2 * (size_t)e1];
            }
            float ex_ = ea.x * we0.x + ea.y * we1.x + beL.x;
            float ey_ = ea.x * we0.y + ea.y * we1.y + beL.y;
            float2 kf = __half22float2(kk.k2);
            float2 vf = __half22float2(kk.v2);
            float p = qv.x * (kf.x + ex_) + qv.y * (kf.y + ey_);
            p += __shfl_xor(p, 1);
            p += __shfl_xor(p, 2);
            p += __shfl_xor(p, 4);
            p += __shfl_xor(p, 8);
            float exv = __expf(p * scale);
            den += exv;
            ax = fmaf(exv, vf.x + ex_, ax);
            ay = fmaf(exv, vf.y + ey_, ay);
        }
        float rden = 1.f / (den + 1e-16f);
        ax *= rden; ay *= rden;
        // beta gate
        float2 xv = *(const float2*)&xr[(size_t)n * 128 + ch];
        float gp = ax * wb_o.x + ay * wb_o.y + xv.x * wb_r.x + xv.y * wb_r.y
                 + (ax - xv.x) * wb_d.x + (ay - xv.y) * wb_d.y;
        gp += __shfl_xor(gp, 1);
        gp += __shfl_xor(gp, 2);
        gp += __shfl_xor(gp, 4);
        gp += __shfl_xor(gp, 8);
        gp += __shfl_xor(gp, 16);
        gp += __shfl_xor(gp, 32);
        float gate = 1.f / (1.f + __expf(-gp));
        float ox = gate * xv.x + (1.f - gate) * ax;
        float oy = gate * xv.y + (1.f - gate) * ay;
        *(float2*)&out2[(size_t)n * 128 + ch] = make_float2(ox, oy);
        bnsx += ox; bnsy += oy;
        bnqx = fmaf(ox, ox, bnqx); bnqy = fmaf(oy, oy, bnqy);
    }
    // block-level BN partial reduce
    __shared__ float s_sum[2][256], s_sq[2][256];
    s_sum[0][t] = bnsx; s_sum[1][t] = bnsy;
    s_sq[0][t] = bnqx;  s_sq[1][t] = bnqy;
    __syncthreads();
    if (t < 64) {
        float sx = s_sum[0][t] + s_sum[0][64 + t] + s_sum[0][128 + t] + s_sum[0][192 + t];
        float sy = s_sum[1][t] + s_sum[1][64 + t] + s_sum[1][128 + t] + s_sum[1][192 + t];
        float qx = s_sq[0][t] + s_sq[0][64 + t] + s_sq[0][128 + t] + s_sq[0][192 + t];
        float qy = s_sq[1][t] + s_sq[1][64 + t] + s_sq[1][128 + t] + s_sq[1][192 + t];
        int c = 2 * t;
        atomicAdd(&bn_accum[c], sx);
        atomicAdd(&bn_accum[c + 1], sy);
        atomicAdd(&bn_accum[128 + c], qx);
        atomicAdd(&bn_accum[128 + c + 1], qy);
    }
}

// ---------------- BN finalize: fold into affine a,b ----------------
__global__ void k_bnfin(const float* __restrict__ bn_accum, const float* __restrict__ gamma,
                        const float* __restrict__ beta, float* __restrict__ ab) {
    int c = threadIdx.x;
    if (c < 128) {
        float mu = bn_accum[c] * (1.f / NN);
        float var = bn_accum[128 + c] * (1.f / NN) - mu * mu;
        float inv = rsqrtf(var + 1e-5f);
        float a = inv * gamma[c];
        ab[c] = a;
        ab[128 + c] = beta[c] - mu * a;
    }
}

// ------- readout: affine+ELU+dot(Wout), LDS per-graph accumulate, one flush per block -------
__global__ __launch_bounds__(256) void k_pool(const float* __restrict__ x, const float* __restrict__ ab,
                                              const float* __restrict__ Wout,
                                              const int* __restrict__ batch,
                                              float* __restrict__ gsum, int* __restrict__ gcnt) {
    __shared__ float lsum[NGRAPH];
    __shared__ int lcnt[NGRAPH];
    int t = threadIdx.x;
    if (t < NGRAPH) { lsum[t] = 0.f; lcnt[t] = 0; }
    __syncthreads();
    int lane = t & 63;
    int wid = t >> 6;
    int ch = lane * 2;
    float2 wo = *(const float2*)&Wout[ch];
    float2 a = *(const float2*)&ab[ch];
    float2 b = *(const float2*)&ab[128 + ch];
    int base = blockIdx.x * 16 + wid * 4;
#pragma unroll
    for (int i = 0; i < 4; i++) {
        int n = base + i;
        if (n < NN) {
            float2 xv = *(const float2*)&x[(size_t)n * 128 + ch];
            float z0 = fmaf(xv.x, a.x, b.x); z0 = z0 > 0.f ? z0 : expm1f(z0);
            float z1 = fmaf(xv.y, a.y, b.y); z1 = z1 > 0.f ? z1 : expm1f(z1);
            float p = z0 * wo.x + z1 * wo.y;
            p += __shfl_xor(p, 1);
            p += __shfl_xor(p, 2);
            p += __shfl_xor(p, 4);
            p += __shfl_xor(p, 8);
            p += __shfl_xor(p, 16);
            p += __shfl_xor(p, 32);
            if (lane == 0) {
                int g = batch[n];
                atomicAdd(&lsum[g], p);
                atomicAdd(&lcnt[g], 1);
            }
        }
    }
    __syncthreads();
    if (t < NGRAPH && lcnt[t] > 0) {
        atomicAdd(&gsum[t], lsum[t]);
        atomicAdd(&gcnt[t], lcnt[t]);
    }
}

__global__ void k_final(const float* __restrict__ gsum, const int* __restrict__ gcnt,
                        const float* __restrict__ bout, const float* __restrict__ obias,
                        float* __restrict__ out) {
    int g = threadIdx.x;
    if (g < NGRAPH) out[g] = gsum[g] / fmaxf((float)gcnt[g], 1.f) + bout[0] + obias[0];
}

extern "C" void kernel_launch(void* const* d_in, const int* in_sizes, int n_in,
                              void* d_out, int out_size, void* d_ws, size_t ws_size,
                              hipStream_t stream) {
    const float* x_in       = (const float*)d_in[0];
    const int* eidx         = (const int*)d_in[1];
    const float* eattr      = (const float*)d_in[2];
    const int* batch        = (const int*)d_in[3];
    const float* Wq         = (const float*)d_in[4];
    const float* bq         = (const float*)d_in[5];
    const float* Wk         = (const float*)d_in[6];
    const float* bk         = (const float*)d_in[7];
    const float* Wv         = (const float*)d_in[8];
    const float* bv         = (const float*)d_in[9];
    const float* We         = (const float*)d_in[10];
    const float* be         = (const float*)d_in[11];
    const float* Wskip      = (const float*)d_in[12];
    const float* bskip      = (const float*)d_in[13];
    const float* Wbeta      = (const float*)d_in[14];
    const float* bn_gamma   = (const float*)d_in[15];
    const float* bn_beta    = (const float*)d_in[16];
    const float* Wout       = (const float*)d_in[17];
    const float* bout       = (const float*)d_in[18];
    const float* obias      = (const float*)d_in[19];
    float* out = (float*)d_out;

    char* ws = (char*)d_ws;
    size_t off = 0;
    auto alloc = [&](size_t bytes) -> void* {
        off = (off + 255) & ~(size_t)255;
        void* p = ws + off;
        off += bytes;
        return p;
    };
    const size_t NF = (size_t)NN * 128 * sizeof(float);
    float* xbuf   = (float*)alloc(NF);
    float* qb     = (float*)alloc(NF);
    float* xrb    = (float*)alloc(NF);
    __half* kvh   = (__half*)alloc((size_t)NN * 256 * sizeof(__half));
    int* row_ptr  = (int*)alloc((NN + 1) * sizeof(int));
    int* cnt      = (int*)alloc(NN * sizeof(int));
    int* elist    = (int*)alloc(EE * sizeof(int));
    float* bn_acc = (float*)alloc(256 * sizeof(float));
    float* bn_ab  = (float*)alloc(256 * sizeof(float));
    float* gsum   = (float*)alloc(64 * sizeof(float));
    int* gcnt     = (int*)alloc(64 * sizeof(int));
    (void)ws_size; (void)n_in; (void)in_sizes; (void)out_size;

    // ---- CSR build (dst -> edge ids) ----
    hipMemsetAsync(cnt, 0, NN * sizeof(int), stream);
    k_deg<<<(EE + 255) / 256, 256, 0, stream>>>(eidx, cnt);
    k_scan<<<1, 1024, 0, stream>>>(cnt, row_ptr);
    hipMemsetAsync(cnt, 0, NN * sizeof(int), stream);
    k_scatter<<<(EE + 255) / 256, 256, 0, stream>>>(eidx, row_ptr, cnt, elist);

    // ---- layers ----
    for (int l = 0; l < 3; ++l) {
        const float* Xl = (l == 0) ? x_in : xbuf;
        hipMemsetAsync(bn_acc, 0, 256 * sizeof(float), stream);
        k_gemm4<<<(NN + 63) / 64, 256, 0, stream>>>(
            Xl,
            Wq + (size_t)l * 16384, bq + l * 128,
            Wk + (size_t)l * 16384, bk + l * 128,
            Wv + (size_t)l * 16384, bv + l * 128,
            Wskip + (size_t)l * 16384, bskip + l * 128,
            bn_ab, (l == 0) ? 0 : 1,
            qb, kvh, xrb);
        k_attn<<<3125, 256, 0, stream>>>(
            qb, kvh, xrb, eidx, eattr, row_ptr, elist,
            We + (size_t)l * 256, be + l * 128, Wbeta + (size_t)l * 384,
            xbuf, bn_acc);
        k_bnfin<<<1, 128, 0, stream>>>(bn_acc, bn_gamma + l * 128, bn_beta + l * 128, bn_ab);
    }

    // ---- readout (affine+ELU of layer-2 BN fused in) ----
    hipMemsetAsync(gsum, 0, 64 * sizeof(float), stream);
    hipMemsetAsync(gcnt, 0, 64 * sizeof(int), stream);
    k_pool<<<(NN + 15) / 16, 256, 0, stream>>>(xbuf, bn_ab, Wout, batch, gsum, gcnt);
    k_final<<<1, 64, 0, stream>>>(gsum, gcnt, bout, obias, out);
}

// Round 4
// 1301.086 us; speedup vs baseline: 1.5602x; 1.0970x over previous
//
#include <hip/hip_runtime.h>
#include <hip/hip_fp16.h>
#include <math.h>

#define NN 50000
#define EE 800000
#define HIDDEN 128
#define NGRAPH 50

struct __align__(8) kv8 { __half2 k2, v2; };

// ---------------- CSR build ----------------
__global__ void k_deg(const int* __restrict__ eidx, int* __restrict__ cnt) {
    int e = blockIdx.x * blockDim.x + threadIdx.x;
    if (e < EE) atomicAdd(&cnt[eidx[EE + e]], 1);
}

__global__ void k_scan(const int* __restrict__ deg, int* __restrict__ row_ptr) {
    __shared__ int wsum[16];
    __shared__ int carry_s;
    int t = threadIdx.x;
    int lane = t & 63, w = t >> 6;
    if (t == 0) carry_s = 0;
    __syncthreads();
    for (int base = 0; base < NN; base += 1024) {
        int i = base + t;
        int v = (i < NN) ? deg[i] : 0;
        int s = v;
#pragma unroll
        for (int o = 1; o < 64; o <<= 1) {
            int u = __shfl_up(s, o);
            if (lane >= o) s += u;
        }
        if (lane == 63) wsum[w] = s;
        __syncthreads();
        if (w == 0) {
            int ws = (lane < 16) ? wsum[lane] : 0;
#pragma unroll
            for (int o = 1; o < 16; o <<= 1) {
                int u = __shfl_up(ws, o);
                if (lane >= o) ws += u;
            }
            if (lane < 16) wsum[lane] = ws;
        }
        __syncthreads();
        int wpre = (w == 0) ? 0 : wsum[w - 1];
        int carry = carry_s;
        if (i < NN) row_ptr[i] = carry + wpre + s - v;   // exclusive scan
        __syncthreads();
        if (t == 1023) carry_s = carry + wpre + s;
        __syncthreads();
    }
    if (t == 0) row_ptr[NN] = carry_s;
}

__global__ void k_scatter(const int* __restrict__ eidx, const int* __restrict__ row_ptr,
                          int* __restrict__ cur, int* __restrict__ elist) {
    int e = blockIdx.x * blockDim.x + threadIdx.x;
    if (e < EE) {
        int d = eidx[EE + e];
        int p = atomicAdd(&cur[d], 1);
        elist[row_ptr[d] + p] = e;
    }
}

// ---- fused 4-way GEMM: q,xr fp32; k,v packed fp16 interleaved. Optional BN-affine+ELU on input. ----
__global__ __launch_bounds__(256) void k_gemm4(
    const float* __restrict__ X,
    const float* __restrict__ Wq, const float* __restrict__ bq,
    const float* __restrict__ Wk, const float* __restrict__ bk,
    const float* __restrict__ Wv, const float* __restrict__ bv,
    const float* __restrict__ Ws, const float* __restrict__ bs,
    const float* __restrict__ ab, int use_ab,
    float* __restrict__ qo, __half* __restrict__ kvh, float* __restrict__ xro)
{
    __shared__ float xs[64][132];
    int t = threadIdx.x;
    int m0 = blockIdx.x * 64;
#pragma unroll
    for (int i = 0; i < 8; ++i) {
        int f = t + 256 * i;          // float4 index within 64x32
        int r = f >> 5, c4 = (f & 31) << 2;
        float4 val = make_float4(0.f, 0.f, 0.f, 0.f);
        if (m0 + r < NN) val = *(const float4*)&X[(size_t)(m0 + r) * 128 + c4];
        if (use_ab) {
            float4 a = *(const float4*)&ab[c4];
            float4 bb = *(const float4*)&ab[128 + c4];
            float z;
            z = fmaf(val.x, a.x, bb.x); val.x = z > 0.f ? z : expm1f(z);
            z = fmaf(val.y, a.y, bb.y); val.y = z > 0.f ? z : expm1f(z);
            z = fmaf(val.z, a.z, bb.z); val.z = z > 0.f ? z : expm1f(z);
            z = fmaf(val.w, a.w, bb.w); val.w = z > 0.f ? z : expm1f(z);
        }
        *(float4*)&xs[r][c4] = val;
    }
    __syncthreads();
    int cg = t & 15, ng = t >> 4;
    int c0 = cg * 8;
    int mb = ng * 4;
    const float* Wm[4] = {Wq, Wk, Wv, Ws};
    const float* bm[4] = {bq, bk, bv, bs};
    __half2 khold[4][4];
#pragma unroll
    for (int w = 0; w < 4; ++w) {
        const float* __restrict__ W = Wm[w];
        float acc[4][8];
#pragma unroll
        for (int i = 0; i < 4; i++)
#pragma unroll
            for (int j = 0; j < 8; j++) acc[i][j] = 0.f;
        for (int k = 0; k < 128; k += 4) {
            float4 xa[4];
#pragma unroll
            for (int i = 0; i < 4; i++) xa[i] = *(const float4*)&xs[mb + i][k];
            float4 wr[4][2];
#pragma unroll
            for (int kk = 0; kk < 4; kk++) {
                wr[kk][0] = *(const float4*)&W[(k + kk) * 128 + c0];
                wr[kk][1] = *(const float4*)&W[(k + kk) * 128 + c0 + 4];
            }
#pragma unroll
            for (int kk = 0; kk < 4; kk++) {
                float wv[8] = {wr[kk][0].x, wr[kk][0].y, wr[kk][0].z, wr[kk][0].w,
                               wr[kk][1].x, wr[kk][1].y, wr[kk][1].z, wr[kk][1].w};
#pragma unroll
                for (int i = 0; i < 4; i++) {
                    float xv = ((const float*)&xa[i])[kk];
#pragma unroll
                    for (int j = 0; j < 8; j++) acc[i][j] = fmaf(xv, wv[j], acc[i][j]);
                }
            }
        }
        float bb[8];
        *(float4*)&bb[0] = *(const float4*)&bm[w][c0];
        *(float4*)&bb[4] = *(const float4*)&bm[w][c0 + 4];
        if (w == 0 || w == 3) {
            float* om = (w == 0) ? qo : xro;
#pragma unroll
            for (int i = 0; i < 4; i++) {
                int node = m0 + mb + i;
                if (node < NN) {
                    float4 o0 = make_float4(acc[i][0] + bb[0], acc[i][1] + bb[1],
                                            acc[i][2] + bb[2], acc[i][3] + bb[3]);
                    float4 o1 = make_float4(acc[i][4] + bb[4], acc[i][5] + bb[5],
                                            acc[i][6] + bb[6], acc[i][7] + bb[7]);
                    *(float4*)&om[(size_t)node * 128 + c0] = o0;
                    *(float4*)&om[(size_t)node * 128 + c0 + 4] = o1;
                }
            }
        } else if (w == 1) {
#pragma unroll
            for (int i = 0; i < 4; i++)
#pragma unroll
                for (int j = 0; j < 4; j++)
                    khold[i][j] = __float22half2_rn(
                        make_float2(acc[i][2 * j] + bb[2 * j], acc[i][2 * j + 1] + bb[2 * j + 1]));
        } else {  // w == 2: interleaved {k0,k1,v0,v1} per channel pair
#pragma unroll
            for (int i = 0; i < 4; i++) {
                int node = m0 + mb + i;
                if (node < NN) {
#pragma unroll
                    for (int j = 0; j < 4; j++) {
                        kv8 p;
                        p.k2 = khold[i][j];
                        p.v2 = __float22half2_rn(
                            make_float2(acc[i][2 * j] + bb[2 * j], acc[i][2 * j + 1] + bb[2 * j + 1]));
                        *(kv8*)&kvh[(size_t)node * 256 + 2 * c0 + 4 * j] = p;
                    }
                }
            }
        }
    }
}

// ---------------- attention + gate + BN-stats (one wave per dst node) ----------------
// Edge loop unrolled x4: 4 kv gathers in flight; index/attr loads are wave-uniform scalar.
__global__ __launch_bounds__(256) void k_attn(
    const float* __restrict__ q, const __half* __restrict__ kvh,
    const float* __restrict__ xr,
    const int* __restrict__ eidx, const float* __restrict__ eattr,
    const int* __restrict__ row_ptr, const int* __restrict__ elist,
    const float* __restrict__ We, const float* __restrict__ be,
    const float* __restrict__ Wb,
    float* __restrict__ out2, float* __restrict__ bn_accum)
{
    int t = threadIdx.x;
    int lane = t & 63;
    int wid = t >> 6;
    int gwave = blockIdx.x * 4 + wid;
    int nwaves = gridDim.x * 4;
    int ch = lane * 2;
    size_t lane8 = 4 * lane;           // half offset within a node's 256-half kv row
    float2 we0 = *(const float2*)&We[ch];
    float2 we1 = *(const float2*)&We[128 + ch];
    float2 beL = *(const float2*)&be[ch];
    float2 wb_o = *(const float2*)&Wb[ch];
    float2 wb_r = *(const float2*)&Wb[128 + ch];
    float2 wb_d = *(const float2*)&Wb[256 + ch];
    const float scale = 0.17677669529663687f;   // 1/sqrt(32)
    float bnsx = 0.f, bnsy = 0.f, bnqx = 0.f, bnqy = 0.f;

    for (int n = gwave; n < NN; n += nwaves) {
        int rs = __builtin_amdgcn_readfirstlane(row_ptr[n]);
        int re = __builtin_amdgcn_readfirstlane(row_ptr[n + 1]);
        float2 qv = *(const float2*)&q[(size_t)n * 128 + ch];
        float den = 0.f;
        float ax = 0.f, ay = 0.f;

        auto edge = [&](int s, float2 ea, kv8 kk) {
            float ex_ = fmaf(ea.x, we0.x, fmaf(ea.y, we1.x, beL.x));
            float ey_ = fmaf(ea.x, we0.y, fmaf(ea.y, we1.y, beL.y));
            float2 kf = __half22float2(kk.k2);
            float2 vf = __half22float2(kk.v2);
            float p = qv.x * (kf.x + ex_) + qv.y * (kf.y + ey_);
            p += __shfl_xor(p, 1);
            p += __shfl_xor(p, 2);
            p += __shfl_xor(p, 4);
            p += __shfl_xor(p, 8);
            float exv = __expf(p * scale);
            den += exv;
            ax = fmaf(exv, vf.x + ex_, ax);
            ay = fmaf(exv, vf.y + ey_, ay);
        };

        int idx = rs;
        for (; idx + 4 <= re; idx += 4) {
            int e0 = __builtin_amdgcn_readfirstlane(elist[idx]);
            int e1 = __builtin_amdgcn_readfirstlane(elist[idx + 1]);
            int e2 = __builtin_amdgcn_readfirstlane(elist[idx + 2]);
            int e3 = __builtin_amdgcn_readfirstlane(elist[idx + 3]);
            int s0 = __builtin_amdgcn_readfirstlane(eidx[e0]);
            int s1 = __builtin_amdgcn_readfirstlane(eidx[e1]);
            int s2 = __builtin_amdgcn_readfirstlane(eidx[e2]);
            int s3 = __builtin_amdgcn_readfirstlane(eidx[e3]);
            kv8 k0 = *(const kv8*)&kvh[(size_t)s0 * 256 + lane8];
            kv8 k1 = *(const kv8*)&kvh[(size_t)s1 * 256 + lane8];
            kv8 k2 = *(const kv8*)&kvh[(size_t)s2 * 256 + lane8];
            kv8 k3 = *(const kv8*)&kvh[(size_t)s3 * 256 + lane8];
            float2 a0 = *(const float2*)&eattr[2 * (size_t)e0];
            float2 a1 = *(const float2*)&eattr[2 * (size_t)e1];
            float2 a2 = *(const float2*)&eattr[2 * (size_t)e2];
            float2 a3 = *(const float2*)&eattr[2 * (size_t)e3];
            edge(s0, a0, k0);
            edge(s1, a1, k1);
            edge(s2, a2, k2);
            edge(s3, a3, k3);
        }
        for (; idx < re; ++idx) {
            int e0 = __builtin_amdgcn_readfirstlane(elist[idx]);
            int s0 = __builtin_amdgcn_readfirstlane(eidx[e0]);
            kv8 k0 = *(const kv8*)&kvh[(size_t)s0 * 256 + lane8];
            float2 a0 = *(const float2*)&eattr[2 * (size_t)e0];
            edge(s0, a0, k0);
        }

        float rden = 1.f / (den + 1e-16f);
        ax *= rden; ay *= rden;
        // beta gate
        float2 xv = *(const float2*)&xr[(size_t)n * 128 + ch];
        float gp = ax * wb_o.x + ay * wb_o.y + xv.x * wb_r.x + xv.y * wb_r.y
                 + (ax - xv.x) * wb_d.x + (ay - xv.y) * wb_d.y;
        gp += __shfl_xor(gp, 1);
        gp += __shfl_xor(gp, 2);
        gp += __shfl_xor(gp, 4);
        gp += __shfl_xor(gp, 8);
        gp += __shfl_xor(gp, 16);
        gp += __shfl_xor(gp, 32);
        float gate = 1.f / (1.f + __expf(-gp));
        float ox = gate * xv.x + (1.f - gate) * ax;
        float oy = gate * xv.y + (1.f - gate) * ay;
        *(float2*)&out2[(size_t)n * 128 + ch] = make_float2(ox, oy);
        bnsx += ox; bnsy += oy;
        bnqx = fmaf(ox, ox, bnqx); bnqy = fmaf(oy, oy, bnqy);
    }
    // block-level BN partial reduce
    __shared__ float s_sum[2][256], s_sq[2][256];
    s_sum[0][t] = bnsx; s_sum[1][t] = bnsy;
    s_sq[0][t] = bnqx;  s_sq[1][t] = bnqy;
    __syncthreads();
    if (t < 64) {
        float sx = s_sum[0][t] + s_sum[0][64 + t] + s_sum[0][128 + t] + s_sum[0][192 + t];
        float sy = s_sum[1][t] + s_sum[1][64 + t] + s_sum[1][128 + t] + s_sum[1][192 + t];
        float qx = s_sq[0][t] + s_sq[0][64 + t] + s_sq[0][128 + t] + s_sq[0][192 + t];
        float qy = s_sq[1][t] + s_sq[1][64 + t] + s_sq[1][128 + t] + s_sq[1][192 + t];
        int c = 2 * t;
        atomicAdd(&bn_accum[c], sx);
        atomicAdd(&bn_accum[c + 1], sy);
        atomicAdd(&bn_accum[128 + c], qx);
        atomicAdd(&bn_accum[128 + c + 1], qy);
    }
}

// ---------------- BN finalize: fold into affine a,b ----------------
__global__ void k_bnfin(const float* __restrict__ bn_accum, const float* __restrict__ gamma,
                        const float* __restrict__ beta, float* __restrict__ ab) {
    int c = threadIdx.x;
    if (c < 128) {
        float mu = bn_accum[c] * (1.f / NN);
        float var = bn_accum[128 + c] * (1.f / NN) - mu * mu;
        float inv = rsqrtf(var + 1e-5f);
        float a = inv * gamma[c];
        ab[c] = a;
        ab[128 + c] = beta[c] - mu * a;
    }
}

// ------- readout: affine+ELU+dot(Wout), LDS per-graph accumulate, one flush per block -------
__global__ __launch_bounds__(256) void k_pool(const float* __restrict__ x, const float* __restrict__ ab,
                                              const float* __restrict__ Wout,
                                              const int* __restrict__ batch,
                                              float* __restrict__ gsum, int* __restrict__ gcnt) {
    __shared__ float lsum[NGRAPH];
    __shared__ int lcnt[NGRAPH];
    int t = threadIdx.x;
    if (t < NGRAPH) { lsum[t] = 0.f; lcnt[t] = 0; }
    __syncthreads();
    int lane = t & 63;
    int wid = t >> 6;
    int ch = lane * 2;
    float2 wo = *(const float2*)&Wout[ch];
    float2 a = *(const float2*)&ab[ch];
    float2 b = *(const float2*)&ab[128 + ch];
    int base = blockIdx.x * 16 + wid * 4;
#pragma unroll
    for (int i = 0; i < 4; i++) {
        int n = base + i;
        if (n < NN) {
            float2 xv = *(const float2*)&x[(size_t)n * 128 + ch];
            float z0 = fmaf(xv.x, a.x, b.x); z0 = z0 > 0.f ? z0 : expm1f(z0);
            float z1 = fmaf(xv.y, a.y, b.y); z1 = z1 > 0.f ? z1 : expm1f(z1);
            float p = z0 * wo.x + z1 * wo.y;
            p += __shfl_xor(p, 1);
            p += __shfl_xor(p, 2);
            p += __shfl_xor(p, 4);
            p += __shfl_xor(p, 8);
            p += __shfl_xor(p, 16);
            p += __shfl_xor(p, 32);
            if (lane == 0) {
                int g = batch[n];
                atomicAdd(&lsum[g], p);
                atomicAdd(&lcnt[g], 1);
            }
        }
    }
    __syncthreads();
    if (t < NGRAPH && lcnt[t] > 0) {
        atomicAdd(&gsum[t], lsum[t]);
        atomicAdd(&gcnt[t], lcnt[t]);
    }
}

__global__ void k_final(const float* __restrict__ gsum, const int* __restrict__ gcnt,
                        const float* __restrict__ bout, const float* __restrict__ obias,
                        float* __restrict__ out) {
    int g = threadIdx.x;
    if (g < NGRAPH) out[g] = gsum[g] / fmaxf((float)gcnt[g], 1.f) + bout[0] + obias[0];
}

extern "C" void kernel_launch(void* const* d_in, const int* in_sizes, int n_in,
                              void* d_out, int out_size, void* d_ws, size_t ws_size,
                              hipStream_t stream) {
    const float* x_in       = (const float*)d_in[0];
    const int* eidx         = (const int*)d_in[1];
    const float* eattr      = (const float*)d_in[2];
    const int* batch        = (const int*)d_in[3];
    const float* Wq         = (const float*)d_in[4];
    const float* bq         = (const float*)d_in[5];
    const float* Wk         = (const float*)d_in[6];
    const float* bk         = (const float*)d_in[7];
    const float* Wv         = (const float*)d_in[8];
    const float* bv         = (const float*)d_in[9];
    const float* We         = (const float*)d_in[10];
    const float* be         = (const float*)d_in[11];
    const float* Wskip      = (const float*)d_in[12];
    const float* bskip      = (const float*)d_in[13];
    const float* Wbeta      = (const float*)d_in[14];
    const float* bn_gamma   = (const float*)d_in[15];
    const float* bn_beta    = (const float*)d_in[16];
    const float* Wout       = (const float*)d_in[17];
    const float* bout       = (const float*)d_in[18];
    const float* obias      = (const float*)d_in[19];
    float* out = (float*)d_out;

    char* ws = (char*)d_ws;
    size_t off = 0;
    auto alloc = [&](size_t bytes) -> void* {
        off = (off + 255) & ~(size_t)255;
        void* p = ws + off;
        off += bytes;
        return p;
    };
    const size_t NF = (size_t)NN * 128 * sizeof(float);
    float* xbuf   = (float*)alloc(NF);
    float* qb     = (float*)alloc(NF);
    float* xrb    = (float*)alloc(NF);
    __half* kvh   = (__half*)alloc((size_t)NN * 256 * sizeof(__half));
    int* row_ptr  = (int*)alloc((NN + 1) * sizeof(int));
    int* cnt      = (int*)alloc(NN * sizeof(int));
    int* elist    = (int*)alloc(EE * sizeof(int));
    float* bn_acc = (float*)alloc(256 * sizeof(float));
    float* bn_ab  = (float*)alloc(256 * sizeof(float));
    float* gsum   = (float*)alloc(64 * sizeof(float));
    int* gcnt     = (int*)alloc(64 * sizeof(int));
    (void)ws_size; (void)n_in; (void)in_sizes; (void)out_size;

    // ---- CSR build (dst -> edge ids) ----
    hipMemsetAsync(cnt, 0, NN * sizeof(int), stream);
    k_deg<<<(EE + 255) / 256, 256, 0, stream>>>(eidx, cnt);
    k_scan<<<1, 1024, 0, stream>>>(cnt, row_ptr);
    hipMemsetAsync(cnt, 0, NN * sizeof(int), stream);
    k_scatter<<<(EE + 255) / 256, 256, 0, stream>>>(eidx, row_ptr, cnt, elist);

    // ---- layers ----
    for (int l = 0; l < 3; ++l) {
        const float* Xl = (l == 0) ? x_in : xbuf;
        hipMemsetAsync(bn_acc, 0, 256 * sizeof(float), stream);
        k_gemm4<<<(NN + 63) / 64, 256, 0, stream>>>(
            Xl,
            Wq + (size_t)l * 16384, bq + l * 128,
            Wk + (size_t)l * 16384, bk + l * 128,
            Wv + (size_t)l * 16384, bv + l * 128,
            Wskip + (size_t)l * 16384, bskip + l * 128,
            bn_ab, (l == 0) ? 0 : 1,
            qb, kvh, xrb);
        k_attn<<<3125, 256, 0, stream>>>(
            qb, kvh, xrb, eidx, eattr, row_ptr, elist,
            We + (size_t)l * 256, be + l * 128, Wbeta + (size_t)l * 384,
            xbuf, bn_acc);
        k_bnfin<<<1, 128, 0, stream>>>(bn_acc, bn_gamma + l * 128, bn_beta + l * 128, bn_ab);
    }

    // ---- readout (affine+ELU of layer-2 BN fused in) ----
    hipMemsetAsync(gsum, 0, 64 * sizeof(float), stream);
    hipMemsetAsync(gcnt, 0, 64 * sizeof(int), stream);
    k_pool<<<(NN + 15) / 16, 256, 0, stream>>>(xbuf, bn_ab, Wout, batch, gsum, gcnt);
    k_final<<<1, 64, 0, stream>>>(gsum, gcnt, bout, obias, out);
}

// Round 5
// 1289.642 us; speedup vs baseline: 1.5740x; 1.0089x over previous
//
#include <hip/hip_runtime.h>
#include <hip/hip_fp16.h>
#include <math.h>

#define NN 50000
#define EE 800000
#define HIDDEN 128
#define NGRAPH 50

struct __align__(8) kv8 { __half2 k2, v2; };

// ---------------- CSR build ----------------
__global__ void k_deg(const int* __restrict__ eidx, int* __restrict__ cnt) {
    int e = blockIdx.x * blockDim.x + threadIdx.x;
    if (e < EE) atomicAdd(&cnt[eidx[EE + e]], 1);
}

__global__ void k_scan(const int* __restrict__ deg, int* __restrict__ row_ptr) {
    __shared__ int wsum[16];
    __shared__ int carry_s;
    int t = threadIdx.x;
    int lane = t & 63, w = t >> 6;
    if (t == 0) carry_s = 0;
    __syncthreads();
    for (int base = 0; base < NN; base += 1024) {
        int i = base + t;
        int v = (i < NN) ? deg[i] : 0;
        int s = v;
#pragma unroll
        for (int o = 1; o < 64; o <<= 1) {
            int u = __shfl_up(s, o);
            if (lane >= o) s += u;
        }
        if (lane == 63) wsum[w] = s;
        __syncthreads();
        if (w == 0) {
            int ws = (lane < 16) ? wsum[lane] : 0;
#pragma unroll
            for (int o = 1; o < 16; o <<= 1) {
                int u = __shfl_up(ws, o);
                if (lane >= o) ws += u;
            }
            if (lane < 16) wsum[lane] = ws;
        }
        __syncthreads();
        int wpre = (w == 0) ? 0 : wsum[w - 1];
        int carry = carry_s;
        if (i < NN) row_ptr[i] = carry + wpre + s - v;   // exclusive scan
        __syncthreads();
        if (t == 1023) carry_s = carry + wpre + s;
        __syncthreads();
    }
    if (t == 0) row_ptr[NN] = carry_s;
}

// scatter: build CSR-ordered src-index and edge-attr arrays (kills indirection in k_attn)
__global__ void k_scatter(const int* __restrict__ eidx, const float* __restrict__ eattr,
                          const int* __restrict__ row_ptr,
                          int* __restrict__ cur, int* __restrict__ esrc, float* __restrict__ eat2) {
    int e = blockIdx.x * blockDim.x + threadIdx.x;
    if (e < EE) {
        int d = eidx[EE + e];
        int s = eidx[e];
        int p = atomicAdd(&cur[d], 1);
        int pos = row_ptr[d] + p;
        esrc[pos] = s;
        float2 ea = *(const float2*)&eattr[2 * (size_t)e];
        *(float2*)&eat2[2 * (size_t)pos] = ea;
    }
}

// ---- fused 4-way GEMM: q,xr fp32; k,v packed fp16 interleaved. Optional BN-affine+ELU on input. ----
__global__ __launch_bounds__(256) void k_gemm4(
    const float* __restrict__ X,
    const float* __restrict__ Wq, const float* __restrict__ bq,
    const float* __restrict__ Wk, const float* __restrict__ bk,
    const float* __restrict__ Wv, const float* __restrict__ bv,
    const float* __restrict__ Ws, const float* __restrict__ bs,
    const float* __restrict__ ab, int use_ab,
    float* __restrict__ qo, __half* __restrict__ kvh, float* __restrict__ xro)
{
    __shared__ float xs[64][132];
    int t = threadIdx.x;
    int m0 = blockIdx.x * 64;
#pragma unroll
    for (int i = 0; i < 8; ++i) {
        int f = t + 256 * i;          // float4 index within 64x32
        int r = f >> 5, c4 = (f & 31) << 2;
        float4 val = make_float4(0.f, 0.f, 0.f, 0.f);
        if (m0 + r < NN) val = *(const float4*)&X[(size_t)(m0 + r) * 128 + c4];
        if (use_ab) {
            float4 a = *(const float4*)&ab[c4];
            float4 bb = *(const float4*)&ab[128 + c4];
            float z;
            z = fmaf(val.x, a.x, bb.x); val.x = z > 0.f ? z : expm1f(z);
            z = fmaf(val.y, a.y, bb.y); val.y = z > 0.f ? z : expm1f(z);
            z = fmaf(val.z, a.z, bb.z); val.z = z > 0.f ? z : expm1f(z);
            z = fmaf(val.w, a.w, bb.w); val.w = z > 0.f ? z : expm1f(z);
        }
        *(float4*)&xs[r][c4] = val;
    }
    __syncthreads();
    int cg = t & 15, ng = t >> 4;
    int c0 = cg * 8;
    int mb = ng * 4;
    const float* Wm[4] = {Wq, Wk, Wv, Ws};
    const float* bm[4] = {bq, bk, bv, bs};
    __half2 khold[4][4];
#pragma unroll
    for (int w = 0; w < 4; ++w) {
        const float* __restrict__ W = Wm[w];
        float acc[4][8];
#pragma unroll
        for (int i = 0; i < 4; i++)
#pragma unroll
            for (int j = 0; j < 8; j++) acc[i][j] = 0.f;
        for (int k = 0; k < 128; k += 4) {
            float4 xa[4];
#pragma unroll
            for (int i = 0; i < 4; i++) xa[i] = *(const float4*)&xs[mb + i][k];
            float4 wr[4][2];
#pragma unroll
            for (int kk = 0; kk < 4; kk++) {
                wr[kk][0] = *(const float4*)&W[(k + kk) * 128 + c0];
                wr[kk][1] = *(const float4*)&W[(k + kk) * 128 + c0 + 4];
            }
#pragma unroll
            for (int kk = 0; kk < 4; kk++) {
                float wv[8] = {wr[kk][0].x, wr[kk][0].y, wr[kk][0].z, wr[kk][0].w,
                               wr[kk][1].x, wr[kk][1].y, wr[kk][1].z, wr[kk][1].w};
#pragma unroll
                for (int i = 0; i < 4; i++) {
                    float xv = ((const float*)&xa[i])[kk];
#pragma unroll
                    for (int j = 0; j < 8; j++) acc[i][j] = fmaf(xv, wv[j], acc[i][j]);
                }
            }
        }
        float bb[8];
        *(float4*)&bb[0] = *(const float4*)&bm[w][c0];
        *(float4*)&bb[4] = *(const float4*)&bm[w][c0 + 4];
        if (w == 0 || w == 3) {
            float* om = (w == 0) ? qo : xro;
#pragma unroll
            for (int i = 0; i < 4; i++) {
                int node = m0 + mb + i;
                if (node < NN) {
                    float4 o0 = make_float4(acc[i][0] + bb[0], acc[i][1] + bb[1],
                                            acc[i][2] + bb[2], acc[i][3] + bb[3]);
                    float4 o1 = make_float4(acc[i][4] + bb[4], acc[i][5] + bb[5],
                                            acc[i][6] + bb[6], acc[i][7] + bb[7]);
                    *(float4*)&om[(size_t)node * 128 + c0] = o0;
                    *(float4*)&om[(size_t)node * 128 + c0 + 4] = o1;
                }
            }
        } else if (w == 1) {
#pragma unroll
            for (int i = 0; i < 4; i++)
#pragma unroll
                for (int j = 0; j < 4; j++)
                    khold[i][j] = __float22half2_rn(
                        make_float2(acc[i][2 * j] + bb[2 * j], acc[i][2 * j + 1] + bb[2 * j + 1]));
        } else {  // w == 2: interleaved {k0,k1,v0,v1} per channel pair
#pragma unroll
            for (int i = 0; i < 4; i++) {
                int node = m0 + mb + i;
                if (node < NN) {
#pragma unroll
                    for (int j = 0; j < 4; j++) {
                        kv8 p;
                        p.k2 = khold[i][j];
                        p.v2 = __float22half2_rn(
                            make_float2(acc[i][2 * j] + bb[2 * j], acc[i][2 * j + 1] + bb[2 * j + 1]));
                        *(kv8*)&kvh[(size_t)node * 256 + 2 * c0 + 4 * j] = p;
                    }
                }
            }
        }
    }
}

// ---------------- attention + gate + BN-stats (one wave per dst node) ----------------
// CSR-ordered esrc/eat2: cooperative lane-load + shfl broadcast; 8 kv gathers in flight.
__global__ __launch_bounds__(256) void k_attn(
    const float* __restrict__ q, const __half* __restrict__ kvh,
    const float* __restrict__ xr,
    const int* __restrict__ esrc, const float* __restrict__ eat2,
    const int* __restrict__ row_ptr,
    const float* __restrict__ We, const float* __restrict__ be,
    const float* __restrict__ Wb,
    float* __restrict__ out2, float* __restrict__ bn_accum)
{
    int t = threadIdx.x;
    int lane = t & 63;
    int wid = t >> 6;
    int gwave = blockIdx.x * 4 + wid;
    int nwaves = gridDim.x * 4;
    int ch = lane * 2;
    size_t lane8 = 4 * lane;           // half offset within a node's 256-half kv row
    float2 we0 = *(const float2*)&We[ch];
    float2 we1 = *(const float2*)&We[128 + ch];
    float2 beL = *(const float2*)&be[ch];
    float2 wb_o = *(const float2*)&Wb[ch];
    float2 wb_r = *(const float2*)&Wb[128 + ch];
    float2 wb_d = *(const float2*)&Wb[256 + ch];
    const float scale = 0.17677669529663687f;   // 1/sqrt(32)
    float bnsx = 0.f, bnsy = 0.f, bnqx = 0.f, bnqy = 0.f;

    for (int n = gwave; n < NN; n += nwaves) {
        int rs = __builtin_amdgcn_readfirstlane(row_ptr[n]);
        int re = __builtin_amdgcn_readfirstlane(row_ptr[n + 1]);
        float2 qv = *(const float2*)&q[(size_t)n * 128 + ch];
        float den = 0.f;
        float ax = 0.f, ay = 0.f;

        auto edge = [&](float eax, float eay, kv8 kk) {
            float ex_ = fmaf(eax, we0.x, fmaf(eay, we1.x, beL.x));
            float ey_ = fmaf(eax, we0.y, fmaf(eay, we1.y, beL.y));
            float2 kf = __half22float2(kk.k2);
            float2 vf = __half22float2(kk.v2);
            float p = qv.x * (kf.x + ex_) + qv.y * (kf.y + ey_);
            p += __shfl_xor(p, 1);
            p += __shfl_xor(p, 2);
            p += __shfl_xor(p, 4);
            p += __shfl_xor(p, 8);
            float exv = __expf(p * scale);
            den += exv;
            ax = fmaf(exv, vf.x + ex_, ax);
            ay = fmaf(exv, vf.y + ey_, ay);
        };

        for (int cb = rs; cb < re; cb += 64) {
            int cnum = re - cb; if (cnum > 64) cnum = 64;
            int mi = cb + lane;
            int sv = 0;
            float2 av = make_float2(0.f, 0.f);
            if (mi < re) {
                sv = esrc[mi];
                av = *(const float2*)&eat2[2 * (size_t)mi];
            }
            int base = 0;
            for (; base + 8 <= cnum; base += 8) {
                int s[8]; float eax[8], eay[8];
#pragma unroll
                for (int j = 0; j < 8; j++) {
                    s[j] = __shfl(sv, base + j);
                    eax[j] = __shfl(av.x, base + j);
                    eay[j] = __shfl(av.y, base + j);
                }
                kv8 kk[8];
#pragma unroll
                for (int j = 0; j < 8; j++)
                    kk[j] = *(const kv8*)&kvh[(size_t)s[j] * 256 + lane8];
#pragma unroll
                for (int j = 0; j < 8; j++) edge(eax[j], eay[j], kk[j]);
            }
            for (; base < cnum; ++base) {
                int s0 = __shfl(sv, base);
                float ex0 = __shfl(av.x, base);
                float ey0 = __shfl(av.y, base);
                kv8 k0 = *(const kv8*)&kvh[(size_t)s0 * 256 + lane8];
                edge(ex0, ey0, k0);
            }
        }

        float rden = 1.f / (den + 1e-16f);
        ax *= rden; ay *= rden;
        // beta gate
        float2 xv = *(const float2*)&xr[(size_t)n * 128 + ch];
        float gp = ax * wb_o.x + ay * wb_o.y + xv.x * wb_r.x + xv.y * wb_r.y
                 + (ax - xv.x) * wb_d.x + (ay - xv.y) * wb_d.y;
        gp += __shfl_xor(gp, 1);
        gp += __shfl_xor(gp, 2);
        gp += __shfl_xor(gp, 4);
        gp += __shfl_xor(gp, 8);
        gp += __shfl_xor(gp, 16);
        gp += __shfl_xor(gp, 32);
        float gate = 1.f / (1.f + __expf(-gp));
        float ox = gate * xv.x + (1.f - gate) * ax;
        float oy = gate * xv.y + (1.f - gate) * ay;
        *(float2*)&out2[(size_t)n * 128 + ch] = make_float2(ox, oy);
        bnsx += ox; bnsy += oy;
        bnqx = fmaf(ox, ox, bnqx); bnqy = fmaf(oy, oy, bnqy);
    }
    // block-level BN partial reduce
    __shared__ float s_sum[2][256], s_sq[2][256];
    s_sum[0][t] = bnsx; s_sum[1][t] = bnsy;
    s_sq[0][t] = bnqx;  s_sq[1][t] = bnqy;
    __syncthreads();
    if (t < 64) {
        float sx = s_sum[0][t] + s_sum[0][64 + t] + s_sum[0][128 + t] + s_sum[0][192 + t];
        float sy = s_sum[1][t] + s_sum[1][64 + t] + s_sum[1][128 + t] + s_sum[1][192 + t];
        float qx = s_sq[0][t] + s_sq[0][64 + t] + s_sq[0][128 + t] + s_sq[0][192 + t];
        float qy = s_sq[1][t] + s_sq[1][64 + t] + s_sq[1][128 + t] + s_sq[1][192 + t];
        int c = 2 * t;
        atomicAdd(&bn_accum[c], sx);
        atomicAdd(&bn_accum[c + 1], sy);
        atomicAdd(&bn_accum[128 + c], qx);
        atomicAdd(&bn_accum[128 + c + 1], qy);
    }
}

// ---------------- BN finalize: fold into affine a,b ----------------
__global__ void k_bnfin(const float* __restrict__ bn_accum, const float* __restrict__ gamma,
                        const float* __restrict__ beta, float* __restrict__ ab) {
    int c = threadIdx.x;
    if (c < 128) {
        float mu = bn_accum[c] * (1.f / NN);
        float var = bn_accum[128 + c] * (1.f / NN) - mu * mu;
        float inv = rsqrtf(var + 1e-5f);
        float a = inv * gamma[c];
        ab[c] = a;
        ab[128 + c] = beta[c] - mu * a;
    }
}

// ------- readout: affine+ELU+dot(Wout), LDS per-graph accumulate, one flush per block -------
__global__ __launch_bounds__(256) void k_pool(const float* __restrict__ x, const float* __restrict__ ab,
                                              const float* __restrict__ Wout,
                                              const int* __restrict__ batch,
                                              float* __restrict__ gsum, int* __restrict__ gcnt) {
    __shared__ float lsum[NGRAPH];
    __shared__ int lcnt[NGRAPH];
    int t = threadIdx.x;
    if (t < NGRAPH) { lsum[t] = 0.f; lcnt[t] = 0; }
    __syncthreads();
    int lane = t & 63;
    int wid = t >> 6;
    int ch = lane * 2;
    float2 wo = *(const float2*)&Wout[ch];
    float2 a = *(const float2*)&ab[ch];
    float2 b = *(const float2*)&ab[128 + ch];
    int base = blockIdx.x * 16 + wid * 4;
#pragma unroll
    for (int i = 0; i < 4; i++) {
        int n = base + i;
        if (n < NN) {
            float2 xv = *(const float2*)&x[(size_t)n * 128 + ch];
            float z0 = fmaf(xv.x, a.x, b.x); z0 = z0 > 0.f ? z0 : expm1f(z0);
            float z1 = fmaf(xv.y, a.y, b.y); z1 = z1 > 0.f ? z1 : expm1f(z1);
            float p = z0 * wo.x + z1 * wo.y;
            p += __shfl_xor(p, 1);
            p += __shfl_xor(p, 2);
            p += __shfl_xor(p, 4);
            p += __shfl_xor(p, 8);
            p += __shfl_xor(p, 16);
            p += __shfl_xor(p, 32);
            if (lane == 0) {
                int g = batch[n];
                atomicAdd(&lsum[g], p);
                atomicAdd(&lcnt[g], 1);
            }
        }
    }
    __syncthreads();
    if (t < NGRAPH && lcnt[t] > 0) {
        atomicAdd(&gsum[t], lsum[t]);
        atomicAdd(&gcnt[t], lcnt[t]);
    }
}

__global__ void k_final(const float* __restrict__ gsum, const int* __restrict__ gcnt,
                        const float* __restrict__ bout, const float* __restrict__ obias,
                        float* __restrict__ out) {
    int g = threadIdx.x;
    if (g < NGRAPH) out[g] = gsum[g] / fmaxf((float)gcnt[g], 1.f) + bout[0] + obias[0];
}

extern "C" void kernel_launch(void* const* d_in, const int* in_sizes, int n_in,
                              void* d_out, int out_size, void* d_ws, size_t ws_size,
                              hipStream_t stream) {
    const float* x_in       = (const float*)d_in[0];
    const int* eidx         = (const int*)d_in[1];
    const float* eattr      = (const float*)d_in[2];
    const int* batch        = (const int*)d_in[3];
    const float* Wq         = (const float*)d_in[4];
    const float* bq         = (const float*)d_in[5];
    const float* Wk         = (const float*)d_in[6];
    const float* bk         = (const float*)d_in[7];
    const float* Wv         = (const float*)d_in[8];
    const float* bv         = (const float*)d_in[9];
    const float* We         = (const float*)d_in[10];
    const float* be         = (const float*)d_in[11];
    const float* Wskip      = (const float*)d_in[12];
    const float* bskip      = (const float*)d_in[13];
    const float* Wbeta      = (const float*)d_in[14];
    const float* bn_gamma   = (const float*)d_in[15];
    const float* bn_beta    = (const float*)d_in[16];
    const float* Wout       = (const float*)d_in[17];
    const float* bout       = (const float*)d_in[18];
    const float* obias      = (const float*)d_in[19];
    float* out = (float*)d_out;

    char* ws = (char*)d_ws;
    size_t off = 0;
    auto alloc = [&](size_t bytes) -> void* {
        off = (off + 255) & ~(size_t)255;
        void* p = ws + off;
        off += bytes;
        return p;
    };
    const size_t NF = (size_t)NN * 128 * sizeof(float);
    float* xbuf   = (float*)alloc(NF);
    float* qb     = (float*)alloc(NF);
    float* xrb    = (float*)alloc(NF);
    __half* kvh   = (__half*)alloc((size_t)NN * 256 * sizeof(__half));
    int* row_ptr  = (int*)alloc((NN + 1) * sizeof(int));
    int* cnt      = (int*)alloc(NN * sizeof(int));
    int* esrc     = (int*)alloc(EE * sizeof(int));
    float* eat2   = (float*)alloc((size_t)EE * 2 * sizeof(float));
    float* bn_acc = (float*)alloc(256 * sizeof(float));
    float* bn_ab  = (float*)alloc(256 * sizeof(float));
    float* gsum   = (float*)alloc(64 * sizeof(float));
    int* gcnt     = (int*)alloc(64 * sizeof(int));
    (void)ws_size; (void)n_in; (void)in_sizes; (void)out_size;

    // ---- CSR build (dst -> src, eattr reordered) ----
    hipMemsetAsync(cnt, 0, NN * sizeof(int), stream);
    k_deg<<<(EE + 255) / 256, 256, 0, stream>>>(eidx, cnt);
    k_scan<<<1, 1024, 0, stream>>>(cnt, row_ptr);
    hipMemsetAsync(cnt, 0, NN * sizeof(int), stream);
    k_scatter<<<(EE + 255) / 256, 256, 0, stream>>>(eidx, eattr, row_ptr, cnt, esrc, eat2);

    // ---- layers ----
    for (int l = 0; l < 3; ++l) {
        const float* Xl = (l == 0) ? x_in : xbuf;
        hipMemsetAsync(bn_acc, 0, 256 * sizeof(float), stream);
        k_gemm4<<<(NN + 63) / 64, 256, 0, stream>>>(
            Xl,
            Wq + (size_t)l * 16384, bq + l * 128,
            Wk + (size_t)l * 16384, bk + l * 128,
            Wv + (size_t)l * 16384, bv + l * 128,
            Wskip + (size_t)l * 16384, bskip + l * 128,
            bn_ab, (l == 0) ? 0 : 1,
            qb, kvh, xrb);
        k_attn<<<3125, 256, 0, stream>>>(
            qb, kvh, xrb, esrc, eat2, row_ptr,
            We + (size_t)l * 256, be + l * 128, Wbeta + (size_t)l * 384,
            xbuf, bn_acc);
        k_bnfin<<<1, 128, 0, stream>>>(bn_acc, bn_gamma + l * 128, bn_beta + l * 128, bn_ab);
    }

    // ---- readout (affine+ELU of layer-2 BN fused in) ----
    hipMemsetAsync(gsum, 0, 64 * sizeof(float), stream);
    hipMemsetAsync(gcnt, 0, 64 * sizeof(int), stream);
    k_pool<<<(NN + 15) / 16, 256, 0, stream>>>(xbuf, bn_ab, Wout, batch, gsum, gcnt);
    k_final<<<1, 64, 0, stream>>>(gsum, gcnt, bout, obias, out);
}